// Round 1
// baseline (61.533 us; speedup 1.0000x reference)
//
#include <hip/hip_runtime.h>

// Cox NLL over N=16384 — SINGLE WORKGROUP, zero grid sync.
//
// Previous version used 64 blocks + two flag-based grid barriers across
// 8 non-coherent XCDs; counters showed the data phase is trivial (192 KB
// read) and ~20 us was cross-XCD sync latency. N=16384 fits one block:
//   1024 threads x 16 elements/thread, scan-then-propagate:
//     1) per-thread serial inclusive prefix of 16 exps (registers)
//     2) wave shuffle scan of 16-wide thread totals (width 64)
//     3) 16 wave totals scanned by wave 0 via LDS
//     4) propagate base, compute sd = ev*(p - log(risk)), block-reduce
// All global loads (4 pred float4 + 8 label float4 per thread) are issued
// before the scan so HBM latency hides under the scan + barriers.
// Workspace is untouched -> poison-immune by construction.

#define NLL_T   1024
#define NLL_PER 16

__global__ __launch_bounds__(NLL_T) void nll_single(const float* __restrict__ pred,
                                                    const float* __restrict__ label,
                                                    float* __restrict__ out) {
    const int tid  = threadIdx.x;
    const int lane = tid & 63;
    const int wave = tid >> 6;                 // 0..15
    const int base = tid * NLL_PER;

    const float4* vp4 = (const float4*)(pred + base);
    const float4* vl4 = (const float4*)(label + 2 * base);

    // ---- issue ALL global loads up front (12 x dwordx4 per thread) ----
    float4 vp[4];
    #pragma unroll
    for (int k = 0; k < 4; ++k) vp[k] = vp4[k];

    float ev[NLL_PER];
    #pragma unroll
    for (int k = 0; k < 8; ++k) {
        float4 v = vl4[k];                     // {time0, ev0, time1, ev1}
        ev[2 * k]     = v.y;
        ev[2 * k + 1] = v.w;
    }

    // ---- per-thread serial inclusive prefix of exp(pred) ----
    float pref[NLL_PER];
    float s = 0.f;
    #pragma unroll
    for (int k = 0; k < 4; ++k) {
        s += __expf(vp[k].x); pref[4 * k + 0] = s;
        s += __expf(vp[k].y); pref[4 * k + 1] = s;
        s += __expf(vp[k].z); pref[4 * k + 2] = s;
        s += __expf(vp[k].w); pref[4 * k + 3] = s;
    }
    const float tot = s;

    // ---- wave-level inclusive scan of per-thread totals ----
    float winc = tot;
    #pragma unroll
    for (int off = 1; off < 64; off <<= 1) {
        float t = __shfl_up(winc, off, 64);
        if (lane >= off) winc += t;
    }

    __shared__ float wsum[16];
    __shared__ float wbase[16];
    if (lane == 63) wsum[wave] = winc;
    __syncthreads();

    // ---- wave 0 scans the 16 wave totals (exclusive) ----
    if (wave == 0) {
        float v = (lane < 16) ? wsum[lane] : 0.f;
        float inc = v;
        #pragma unroll
        for (int off = 1; off < 16; off <<= 1) {
            float t = __shfl_up(inc, off, 64);
            if (lane >= off) inc += t;
        }
        if (lane < 16) wbase[lane] = inc - v;  // exclusive base per wave
    }
    __syncthreads();

    // exclusive prefix at this thread's first element
    const float tbase = wbase[wave] + (winc - tot);

    // ---- fused masked sums: sd = ev*(p - log(risk)), se = ev ----
    float sd = 0.f, se = 0.f;
    #pragma unroll
    for (int k = 0; k < 4; ++k) {
        const float e0 = ev[4 * k + 0], e1 = ev[4 * k + 1];
        const float e2 = ev[4 * k + 2], e3 = ev[4 * k + 3];
        sd += e0 * (vp[k].x - __logf(tbase + pref[4 * k + 0]));
        sd += e1 * (vp[k].y - __logf(tbase + pref[4 * k + 1]));
        sd += e2 * (vp[k].z - __logf(tbase + pref[4 * k + 2]));
        sd += e3 * (vp[k].w - __logf(tbase + pref[4 * k + 3]));
        se += e0 + e1 + e2 + e3;
    }

    // ---- block reduction ----
    #pragma unroll
    for (int off = 32; off > 0; off >>= 1) {
        sd += __shfl_down(sd, off, 64);
        se += __shfl_down(se, off, 64);
    }
    __shared__ float rd[16], re[16];
    if (lane == 0) { rd[wave] = sd; re[wave] = se; }
    __syncthreads();

    if (tid == 0) {
        float d = 0.f, n = 0.f;
        #pragma unroll
        for (int w = 0; w < 16; ++w) { d += rd[w]; n += re[w]; }
        out[1] = n;                                        // n_observed
        out[0] = (n == 0.f) ? 0.f : -(d / fmaxf(n, 1.f));  // cost
    }
}

extern "C" void kernel_launch(void* const* d_in, const int* in_sizes, int n_in,
                              void* d_out, int out_size, void* d_ws, size_t ws_size,
                              hipStream_t stream) {
    const float* pred  = (const float*)d_in[0];   // (N,1) float32
    const float* label = (const float*)d_in[1];   // (N,2) float32
    float* out = (float*)d_out;                   // [cost, n_observed]
    (void)in_sizes; (void)n_in; (void)out_size; (void)d_ws; (void)ws_size;
    nll_single<<<1, NLL_T, 0, stream>>>(pred, label, out);
}